// Round 6
// baseline (88.681 us; speedup 1.0000x reference)
//
#include <hip/hip_runtime.h>
#include <math.h>

// FrequencyMaskingLoss — psychoacoustic masking loss (forward only, scalar out).
// Pipeline (4 launches):
//   [K0] <<<3,256>>>       constant tables (f64 math), block-specialized
//   [K1] <<<ceil(nf/4),256>>> STFT — ONE WAVE PER FRAME register FFT:
//        8 complex elems/lane; stages 1-3 in-lane, stages 4-9 via __shfl_xor
//        (dist 1..32, all in-wave on wave64). No barriers after twiddle load,
//        no data LDS. Twiddle LDS uses a^(a>>5) index swizzle (conflict-free
//        gathers at stages 7-9). Butterfly order/twiddles/expressions identical
//        to the proven round-4 network -> bitwise-identical spectra.
//        Unpack z[k]<->z[512-k] via shfl_xor(63) (63-l == l^63) + one indexed
//        shfl for the j==0 column. 4 frames per block.
//   [K3] <<<nf,256>>>      fused global-max + masking threshold + loss partial
//        (round-4 verbatim: bitwise-same pmax, pipelined serial scan)
//   [K4] <<<1,256>>>       mean -> out[0]
// WINDOW=512, HOP=128, F=257, n_frames=(L-512)/128+1 (=1247 for L=160000).

#define FBINS 257

// table layout inside ws (floats): barkf[257] | athdb[257] | athp[257] |
//                                  hann[512] | twr[256] | twi[256]
#define TAB_BARK  0
#define TAB_ATHDB 257
#define TAB_ATHP  514
#define TAB_HANN  771
#define TAB_TWR   1283
#define TAB_TWI   1539
#define TAB_FLOATS 2048   // padded

// ---------------------------------------------------------------- kernel 0
// 3 blocks on 3 CUs: block0 = freq tables, block1 = hann, block2 = twiddles.
__global__ __launch_bounds__(256) void k0_init(float* __restrict__ tab)
{
    const int tid = threadIdx.x;
    const double TWO_PI = 6.283185307179586476925286766559;
    if (blockIdx.x == 0) {
        for (int f = tid; f < FBINS; f += 256) {
            double freq = 31.25 * (double)f;            // SR/2/256 * f, exact
            double q    = freq / 7500.0;
            tab[TAB_BARK + f] = (float)(13.0 * atan(0.00076 * freq) + 3.5 * atan(q * q));
            if (f == 0) {
                tab[TAB_ATHDB] = -INFINITY;
                tab[TAB_ATHP]  = 0.0f;
            } else {
                double fk = freq * 0.001;
                double ad = 3.64 * pow(fk, -0.8)
                          - 6.5 * exp(-0.6 * (fk - 3.3) * (fk - 3.3))
                          + 0.001 * fk * fk * fk * fk - 12.0;
                float av = (float)ad;
                tab[TAB_ATHDB + f] = av;
                tab[TAB_ATHP  + f] = exp10f(av / 10.0f);
            }
        }
    } else if (blockIdx.x == 1) {
        for (int n = tid; n < 512; n += 256) {
            double cw = cos((TWO_PI * (double)n) / 512.0);
            tab[TAB_HANN + n] = (float)(0.5 * (1.0 - cw));
        }
    } else {
        for (int j = tid; j < 256; j += 256) {
            double s, c;
            sincos(-(TWO_PI / 512.0) * (double)j, &s, &c);
            tab[TAB_TWR + j] = (float)c;
            tab[TAB_TWI + j] = (float)s;
        }
    }
}

// ---------------------------------------------------------------- kernel 1
// Wave-per-frame 512-pt complex FFT (z = hann*ref + i*hann*delta).
// Lane l holds bit-reversed-array elements e = 8l+j (j=0..7) in VGPRs.
__global__ __launch_bounds__(256) void k1_stft(
    const float* __restrict__ xadv, const float* __restrict__ xref,
    const float* __restrict__ tab, int nf,
    float* __restrict__ psd_db, float* __restrict__ pd, float* __restrict__ fmaxs)
{
    __shared__ float twr_s[256], twi_s[256];
    const int tid = threadIdx.x, lane = tid & 63, wid = tid >> 6;

    {   // swizzled twiddle staging: phys = a ^ (a>>5) -> conflict-free FFT gathers
        int a = tid;
        int p = a ^ (a >> 5);
        twr_s[p] = tab[TAB_TWR + a];
        twi_s[p] = tab[TAB_TWI + a];
    }
    __syncthreads();                       // only barrier in the kernel

    const int frame = blockIdx.x * 4 + wid;
    if (frame >= nf) return;

    // bit-reversed load: e = 8l+j  ->  sample n = brev6(l) + 64*brev3(j).
    // For fixed j the 64 lanes cover one contiguous 256B block (permuted) -> coalesced.
    const int base_idx = frame * 128;
    const int nl = (int)(__brev((unsigned)lane) >> 26);   // brev6(lane)
    float2 E[8];
    #pragma unroll
    for (int j = 0; j < 8; ++j) {
        int bj = (int)(__brev((unsigned)j) >> 29);        // brev3(j)
        int n  = nl + (bj << 6);
        float w = tab[TAB_HANN + n];
        float r = xref[base_idx + n];
        float a = xadv[base_idx + n];
        E[j] = make_float2(w * r, w * (a - r));
    }

    // in-lane butterfly with the exact round-4 expressions
#define BFLY(U, V, WR, WI)                                   \
    {                                                        \
        float vr = (V).x * (WR) - (V).y * (WI);              \
        float vi = (V).x * (WI) + (V).y * (WR);              \
        float ur = (U).x, ui = (U).y;                        \
        (U) = make_float2(ur + vr, ui + vi);                 \
        (V) = make_float2(ur - vr, ui - vi);                 \
    }

    // stage 1 (dist 1): twiddle index 0 for all pairs
    {
        float wr = twr_s[0], wi = twi_s[0];
        BFLY(E[0], E[1], wr, wi); BFLY(E[2], E[3], wr, wi);
        BFLY(E[4], E[5], wr, wi); BFLY(E[6], E[7], wr, wi);
    }
    // stage 2 (dist 2): idx = (pbase&1)*128
    {
        int p0 = 0 ^ (0 >> 5), p1 = 128 ^ (128 >> 5);
        float wr0 = twr_s[p0], wi0 = twi_s[p0];
        float wr1 = twr_s[p1], wi1 = twi_s[p1];
        BFLY(E[0], E[2], wr0, wi0); BFLY(E[1], E[3], wr1, wi1);
        BFLY(E[4], E[6], wr0, wi0); BFLY(E[5], E[7], wr1, wi1);
    }
    // stage 3 (dist 4): idx = (pbase&3)*64
    {
        #pragma unroll
        for (int pb = 0; pb < 4; ++pb) {
            int a = pb * 64, p = a ^ (a >> 5);
            float wr = twr_s[p], wi = twi_s[p];
            BFLY(E[pb], E[pb + 4], wr, wi);
        }
    }
    // stages 4..9: lane-exchange distance d = 1<<(s-4); all in-wave (<=32)
    #pragma unroll
    for (int s = 4; s <= 9; ++s) {
        const int d    = 1 << (s - 4);
        const int half = 1 << (s - 1);
        const int tst  = 512 >> s;
        const int b    = (lane >> (s - 4)) & 1;
        #pragma unroll
        for (int j = 0; j < 8; ++j) {
            int a = ((8 * lane + j) & (half - 1)) * tst;   // same for both partners
            int p = a ^ (a >> 5);
            float wr = twr_s[p], wi = twi_s[p];
            float ox = __shfl_xor(E[j].x, d);
            float oy = __shfl_xor(E[j].y, d);
            float ux = b ? ox : E[j].x;
            float uy = b ? oy : E[j].y;
            float vx = b ? E[j].x : ox;
            float vy = b ? E[j].y : oy;
            float vr = vx * wr - vy * wi;
            float vi = vx * wi + vy * wr;
            E[j] = b ? make_float2(ux - vr, uy - vi)
                     : make_float2(ux + vr, uy + vi);
        }
    }
#undef BFLY
    // lane l now holds z[8l..8l+7] (natural order)

    // unpack partners: z[512-(8l+j)] = lane(63-l).E[8-j] for j>=1 (63-l == l^63);
    // z[(512-8l)&511] = lane((64-l)&63).E[0] for j==0.
    float2 Zn[8];
    #pragma unroll
    for (int j = 1; j < 8; ++j) {
        Zn[j].x = __shfl_xor(E[8 - j].x, 63);
        Zn[j].y = __shfl_xor(E[8 - j].y, 63);
    }
    {
        int src = (64 - lane) & 63;
        Zn[0].x = __shfl(E[0].x, src);
        Zn[0].y = __shfl(E[0].y, src);
    }

    const float S2 = 1.0172526041666667e-05f;   // (sqrt(8/3)/512)^2
    float lmax = -1e30f;
    if (lane <= 32) {
        #pragma unroll
        for (int j = 0; j < 8; ++j) {
            int k = 8 * lane + j;
            if (k <= 256) {
                float2 zk = E[j], zn = Zn[j];
                float ar = 0.5f * (zk.x + zn.x), ai = 0.5f * (zk.y - zn.y);
                float br = 0.5f * (zk.y + zn.y), bi = 0.5f * (zn.x - zk.x);
                float prefp = S2 * (ar * ar + ai * ai);
                float pdb   = fmaxf(10.0f * log10f(prefp), -200.0f);
                psd_db[frame * FBINS + k] = pdb;
                pd[frame * FBINS + k]     = S2 * (br * br + bi * bi);
                lmax = fmaxf(lmax, pdb);
            }
        }
    }
    for (int off = 32; off > 0; off >>= 1) lmax = fmaxf(lmax, __shfl_down(lmax, off));
    if (lane == 0) fmaxs[frame] = lmax;        // exact max: order-free
}

// ---------------------------------------------------------------- kernel 3
// (round-4 verbatim) fused global-max + threshold + loss partial.
__global__ __launch_bounds__(256) void k3_threshold(
    const float* __restrict__ tab,
    const float* __restrict__ psd_db, const float* __restrict__ pd,
    const float* __restrict__ fmaxs, int nf, float* __restrict__ floss)
{
    __shared__ float barkf[FBINS], athp_s[FBINS];
    __shared__ float p_s[FBINS], pw_s[FBINS];
    __shared__ float mc_s[128], shift_s[128], barkm_s[128], ups_s[128];
    __shared__ int   bin_s[128], keep_s[128];
    __shared__ float2 pmk[132];
    __shared__ int   wcnt[4];
    __shared__ float red[4];
    __shared__ float sm[4];

    const int t = blockIdx.x, tid = threadIdx.x;
    const int lane = tid & 63, wid = tid >> 6;

    const float pdb_a = psd_db[t * FBINS + tid];
    const float pdb_b = psd_db[t * FBINS + 256];

    for (int f = tid; f < FBINS; f += 256) {
        barkf[f]  = tab[TAB_BARK + f];
        athp_s[f] = tab[TAB_ATHP + f];
    }
    float v = -1e30f;
    for (int i = tid; i < nf; i += 256) v = fmaxf(v, fmaxs[i]);
    for (int off = 32; off > 0; off >>= 1) v = fmaxf(v, __shfl_down(v, off));
    if (lane == 0) sm[wid] = v;
    __syncthreads();
    const float pmax   = fmaxf(fmaxf(sm[0], sm[1]), fmaxf(sm[2], sm[3]));
    const float shift0 = 96.0f - pmax;

    {
        float pv = shift0 + pdb_a;
        p_s[tid]  = pv;
        pw_s[tid] = exp10f(pv / 10.0f);
        if (tid == 0) {
            float pv2 = shift0 + pdb_b;
            p_s[256]  = pv2;
            pw_s[256] = exp10f(pv2 / 10.0f);
        }
    }
    __syncthreads();

    float m = -1e30f;
    int   pred = 0;
    if (tid >= 1 && tid <= 255) {
        float pc = p_s[tid];
        if (pc > p_s[tid - 1] && pc > p_s[tid + 1]) {
            m = 10.0f * log10f((pw_s[tid] + pw_s[tid - 1]) + pw_s[tid + 1]);
            if (m > tab[TAB_ATHDB + tid]) pred = 1;
        }
    }
    unsigned long long bal = __ballot(pred);
    if (lane == 0) wcnt[wid] = __popcll(bal);
    __syncthreads();
    int base = 0;
    for (int w = 0; w < wid; ++w) base += wcnt[w];
    const int n_total = wcnt[0] + wcnt[1] + wcnt[2] + wcnt[3];
    if (pred) {
        int pos = base + __popcll(bal & ((1ull << lane) - 1));
        bin_s[pos] = tid; mc_s[pos] = m; keep_s[pos] = 1;
    }
    __syncthreads();

    if (tid <= n_total && tid < 130) {
        pmk[tid] = (tid < n_total) ? make_float2(barkf[tid], mc_s[tid])
                                   : make_float2(1.0e30f, -1.0e30f);
    }
    __syncthreads();

    if (tid == 0 && n_total > 1) {
        int   i_prev = 0;
        float bp = pmk[0].x, mp = pmk[0].y;
        float2 c = pmk[1];
        for (int i = 1; i < n_total; ++i) {
            float2 nx = pmk[i + 1];
            bool close        = (c.x - bp) < 0.5f;
            bool prev_smaller = mp < c.y;
            if (close) {
                keep_s[prev_smaller ? i_prev : i] = 0;
                if (prev_smaller) {
                    ++i_prev;
                    if (i_prev == i) { bp = c.x; mp = c.y; }
                    else { float2 p = pmk[i_prev]; bp = p.x; mp = p.y; }
                }
            } else {
                i_prev = i; bp = c.x; mp = c.y;
            }
            c = nx;
        }
    }
    __syncthreads();

    int pred2 = (tid < n_total) && keep_s[tid];
    unsigned long long bal2 = __ballot(pred2);
    if (lane == 0) wcnt[wid] = __popcll(bal2);
    __syncthreads();
    int base2 = 0;
    for (int w = 0; w < wid; ++w) base2 += wcnt[w];
    const int nk = wcnt[0] + wcnt[1] + wcnt[2] + wcnt[3];
    if (pred2) {
        int pos = base2 + __popcll(bal2 & ((1ull << lane) - 1));
        int   fb = bin_s[tid];
        float mc = mc_s[tid];
        shift_s[pos] = mc + (-6.025f - 0.275f * barkf[fb]);
        barkm_s[pos] = barkf[fb];
        ups_s[pos]   = -27.0f + 0.37f * fmaxf(mc - 40.0f, 0.0f);
    }
    __syncthreads();

    const float C = 3981071705.534973f / exp10f(pmax / 10.0f);  // 10^9.6/10^(pmax/10)
    float lsum = 0.0f;
    for (int f = tid; f < FBINS; f += 256) {
        float bf  = barkf[f];
        float acc = 0.0f;
        for (int k = 0; k < nk; ++k) {
            float dz    = bf - barkm_s[k];
            float slope = (dz > 0.0f) ? ups_s[k] : 27.0f;
            float tdb   = shift_s[k] + slope * dz;
            acc += exp10f(tdb / 10.0f);
        }
        float thrpow = acc + athp_s[f];
        float pds    = C * pd[t * FBINS + f];
        lsum += fmaxf(pds - thrpow, 0.0f);
    }
    for (int off = 32; off > 0; off >>= 1) lsum += __shfl_down(lsum, off);
    if ((tid & 63) == 0) red[tid >> 6] = lsum;
    __syncthreads();
    if (tid == 0) floss[t] = (red[0] + red[1]) + (red[2] + red[3]);
}

// ---------------------------------------------------------------- kernel 4
__global__ __launch_bounds__(256) void k4_final(
    const float* __restrict__ floss, int nf, float* __restrict__ out)
{
    __shared__ float red[4];
    float s = 0.0f;
    for (int i = threadIdx.x; i < nf; i += 256) s += floss[i];
    for (int off = 32; off > 0; off >>= 1) s += __shfl_down(s, off);
    if ((threadIdx.x & 63) == 0) red[threadIdx.x >> 6] = s;
    __syncthreads();
    if (threadIdx.x == 0) {
        float total = (red[0] + red[1]) + (red[2] + red[3]);
        out[0] = 1e-6f * (total / (float)(nf * FBINS));
    }
}

// ---------------------------------------------------------------- launch
extern "C" void kernel_launch(void* const* d_in, const int* in_sizes, int n_in,
                              void* d_out, int out_size, void* d_ws, size_t ws_size,
                              hipStream_t stream)
{
    const float* x_adv = (const float*)d_in[0];
    const float* x_ref = (const float*)d_in[1];
    float*       out   = (float*)d_out;

    const int L  = in_sizes[0];
    const int nf = (L - 512) / 128 + 1;           // 1247 for L=160000

    // workspace layout (floats)
    float* ws      = (float*)d_ws;
    float* tab     = ws;                                   // TAB_FLOATS
    float* psd_db  = ws + TAB_FLOATS;                      // nf*257
    float* pd      = psd_db + (size_t)nf * FBINS;          // nf*257
    float* fmaxs   = pd + (size_t)nf * FBINS;              // nf
    float* floss   = fmaxs + nf;                           // nf

    const int k1_blocks = (nf + 3) / 4;           // 4 frames (waves) per block

    k0_init     <<<3,         256, 0, stream>>>(tab);
    k1_stft     <<<k1_blocks, 256, 0, stream>>>(x_adv, x_ref, tab, nf, psd_db, pd, fmaxs);
    k3_threshold<<<nf,        256, 0, stream>>>(tab, psd_db, pd, fmaxs, nf, floss);
    k4_final    <<<1,         256, 0, stream>>>(floss, nf, out);
}

// Round 7
// 86.886 us; speedup vs baseline: 1.0207x; 1.0207x over previous
//
#include <hip/hip_runtime.h>
#include <math.h>

// FrequencyMaskingLoss — psychoacoustic masking loss (forward only, scalar out).
// Pipeline (4 launches):
//   [K0] <<<3,256>>>   constant tables (f64 math), block-specialized
//   [K1] <<<nf,256>>>  STFT — round-4 PROVEN kernel verbatim (register/shuffle
//        FFT, 2 elems/thread, 5 barriers). NOTE: round-6 showed wave-per-frame
//        shfl FFT regresses: __shfl == ds_bpermute on CDNA (same LDS hw),
//        ~112 DS-ops/lane vs ~32 here.
//   [K3] <<<ceil(nf/2),512>>> threshold — TWO frames per block: halves the
//        per-block frame-invariant work (bark/ATH table loads, 1247-wide fmaxs
//        max-reduce, barrier count) and runs the two serial i_prev scans
//        concurrently. Per-frame math + reduction order bitwise == round 4.
//   [K4] <<<1,256>>>   mean -> out[0]
// WINDOW=512, HOP=128, F=257, n_frames=(L-512)/128+1 (=1247 for L=160000).

#define FBINS 257

// table layout inside ws (floats): barkf[257] | athdb[257] | athp[257] |
//                                  hann[512] | twr[256] | twi[256]
#define TAB_BARK  0
#define TAB_ATHDB 257
#define TAB_ATHP  514
#define TAB_HANN  771
#define TAB_TWR   1283
#define TAB_TWI   1539
#define TAB_FLOATS 2048   // padded

// ---------------------------------------------------------------- kernel 0
// 3 blocks on 3 CUs: block0 = freq tables, block1 = hann, block2 = twiddles.
__global__ __launch_bounds__(256) void k0_init(float* __restrict__ tab)
{
    const int tid = threadIdx.x;
    const double TWO_PI = 6.283185307179586476925286766559;
    if (blockIdx.x == 0) {
        for (int f = tid; f < FBINS; f += 256) {
            double freq = 31.25 * (double)f;            // SR/2/256 * f, exact
            double q    = freq / 7500.0;
            tab[TAB_BARK + f] = (float)(13.0 * atan(0.00076 * freq) + 3.5 * atan(q * q));
            if (f == 0) {
                tab[TAB_ATHDB] = -INFINITY;
                tab[TAB_ATHP]  = 0.0f;
            } else {
                double fk = freq * 0.001;
                double ad = 3.64 * pow(fk, -0.8)
                          - 6.5 * exp(-0.6 * (fk - 3.3) * (fk - 3.3))
                          + 0.001 * fk * fk * fk * fk - 12.0;
                float av = (float)ad;
                tab[TAB_ATHDB + f] = av;
                tab[TAB_ATHP  + f] = exp10f(av / 10.0f);
            }
        }
    } else if (blockIdx.x == 1) {
        for (int n = tid; n < 512; n += 256) {
            double cw = cos((TWO_PI * (double)n) / 512.0);
            tab[TAB_HANN + n] = (float)(0.5 * (1.0 - cw));
        }
    } else {
        for (int j = tid; j < 256; j += 256) {
            double s, c;
            sincos(-(TWO_PI / 512.0) * (double)j, &s, &c);
            tab[TAB_TWR + j] = (float)c;
            tab[TAB_TWI + j] = (float)s;
        }
    }
}

// ---------------------------------------------------------------- kernel 1
// (round-4 verbatim) One frame per block; z = hann*ref + i*hann*delta ->
// one 512-pt complex FFT. Register-resident radix-2 DIT, 2 elems/thread.
__global__ __launch_bounds__(256) void k1_stft(
    const float* __restrict__ xadv, const float* __restrict__ xref,
    const float* __restrict__ tab,
    float* __restrict__ psd_db, float* __restrict__ pd, float* __restrict__ fmaxs)
{
    __shared__ float2 tw2[256];
    __shared__ float2 bufA[256], bufB[256];
    __shared__ float2 zf[512];
    __shared__ float wmax[4];
    const int t = blockIdx.x, tid = threadIdx.x;

    tw2[tid] = make_float2(tab[TAB_TWR + tid], tab[TAB_TWI + tid]);

    const int base_idx = t * 128;
    const int n0 = (int)(__brev((unsigned)tid) >> 24);
    const int n1 = n0 + 256;
    float w0 = tab[TAB_HANN + n0], w1 = tab[TAB_HANN + n1];
    float r0 = xref[base_idx + n0], r1 = xref[base_idx + n1];
    float a0 = xadv[base_idx + n0], a1 = xadv[base_idx + n1];
    float2 E0 = make_float2(w0 * r0, w0 * (a0 - r0));
    float2 E1 = make_float2(w1 * r1, w1 * (a1 - r1));
    __syncthreads();

    #pragma unroll
    for (int s = 1; s <= 7; ++s) {
        const int half  = 1 << (s - 1);
        const int tstep = 512 >> s;
        float2 w = tw2[(tid & (half - 1)) * tstep];
        float vr = E1.x * w.x - E1.y * w.y;
        float vi = E1.x * w.y + E1.y * w.x;
        float ur = E0.x, ui = E0.y;
        E0 = make_float2(ur + vr, ui + vi);
        E1 = make_float2(ur - vr, ui - vi);
        if (s <= 6) {
            const int d = 1 << (s - 1);
            int b = (tid >> (s - 1)) & 1;
            float2 keep = b ? E1 : E0;
            float2 send = b ? E0 : E1;
            float2 recv;
            recv.x = __shfl_xor(send.x, d);
            recv.y = __shfl_xor(send.y, d);
            E0 = b ? recv : keep;
            E1 = b ? keep : recv;
        }
    }
    {
        int b = (tid >> 6) & 1;
        float2 keep = b ? E1 : E0;
        bufA[tid] = b ? E0 : E1;
        __syncthreads();
        float2 recv = bufA[tid ^ 64];
        E0 = b ? recv : keep;
        E1 = b ? keep : recv;
    }
    {
        float2 w = tw2[(tid & 127) * 2];
        float vr = E1.x * w.x - E1.y * w.y;
        float vi = E1.x * w.y + E1.y * w.x;
        float ur = E0.x, ui = E0.y;
        E0 = make_float2(ur + vr, ui + vi);
        E1 = make_float2(ur - vr, ui - vi);
    }
    {
        int b = (tid >> 7) & 1;
        float2 keep = b ? E1 : E0;
        bufB[tid] = b ? E0 : E1;
        __syncthreads();
        float2 recv = bufB[tid ^ 128];
        E0 = b ? recv : keep;
        E1 = b ? keep : recv;
    }
    {
        float2 w = tw2[tid];
        float vr = E1.x * w.x - E1.y * w.y;
        float vi = E1.x * w.y + E1.y * w.x;
        float ur = E0.x, ui = E0.y;
        E0 = make_float2(ur + vr, ui + vi);
        E1 = make_float2(ur - vr, ui - vi);
    }
    zf[tid]       = E0;
    zf[tid + 256] = E1;
    __syncthreads();

    const float S2 = 1.0172526041666667e-05f;   // (sqrt(8/3)/512)^2
    float lmax = -1e30f;
    for (int k = tid; k <= 256; k += 256) {
        int nk = (512 - k) & 511;
        float2 zk = zf[k];
        float2 zn = zf[nk];
        float ar = 0.5f * (zk.x + zn.x), ai = 0.5f * (zk.y - zn.y);
        float br = 0.5f * (zk.y + zn.y), bi = 0.5f * (zn.x - zk.x);
        float prefp = S2 * (ar * ar + ai * ai);
        float pdb   = fmaxf(10.0f * log10f(prefp), -200.0f);
        psd_db[t * FBINS + k] = pdb;
        pd[t * FBINS + k]     = S2 * (br * br + bi * bi);
        lmax = fmaxf(lmax, pdb);
    }
    for (int off = 32; off > 0; off >>= 1) lmax = fmaxf(lmax, __shfl_down(lmax, off));
    if ((tid & 63) == 0) wmax[tid >> 6] = lmax;
    __syncthreads();
    if (tid == 0)
        fmaxs[t] = fmaxf(fmaxf(wmax[0], wmax[1]), fmaxf(wmax[2], wmax[3]));
}

// ---------------------------------------------------------------- kernel 3
// TWO frames per 512-thread block. Group g = tid>>8 (0: waves 0-3, 1: waves
// 4-7), tid_l = tid&255 inside the group. Per-group code is the round-4 k3
// verbatim; bark/ATH tables and pmax are computed once per block (pmax via
// tid_l so both groups reproduce k2's exact reduction order -> bitwise same).
__global__ __launch_bounds__(512) void k3_threshold(
    const float* __restrict__ tab,
    const float* __restrict__ psd_db, const float* __restrict__ pd,
    const float* __restrict__ fmaxs, int nf, float* __restrict__ floss)
{
    __shared__ float barkf[FBINS], athp_s[FBINS];        // frame-invariant
    __shared__ float p_s[2][FBINS], pw_s[2][FBINS];
    __shared__ float mc_s[2][128], shift_s[2][128], barkm_s[2][128], ups_s[2][128];
    __shared__ int   bin_s[2][128], keep_s[2][128];
    __shared__ float2 pmk[2][132];
    __shared__ int   wcnt[2][4];
    __shared__ float red[2][4];
    __shared__ float sm[4];

    const int tid   = threadIdx.x;
    const int g     = tid >> 8;            // frame slot in block
    const int tid_l = tid & 255;
    const int lane  = tid & 63;
    const int wid_l = (tid >> 6) & 3;      // wave within group

    int frame = blockIdx.x * 2 + g;
    if (frame > nf - 1) frame = nf - 1;    // last block may duplicate nf-1 (benign)

    // prefetch this frame's PSD bins (overlap latency with the max reduce)
    const float pdb_a = psd_db[frame * FBINS + tid_l];
    const float pdb_b = psd_db[frame * FBINS + 256];

    // frame-invariant tables, once per block
    for (int f = tid; f < FBINS; f += 512) {
        barkf[f]  = tab[TAB_BARK + f];
        athp_s[f] = tab[TAB_ATHP + f];
    }
    // global psd_max — k2's exact order (tid_l stride 256; group 1 duplicates)
    float v = -1e30f;
    for (int i = tid_l; i < nf; i += 256) v = fmaxf(v, fmaxs[i]);
    for (int off = 32; off > 0; off >>= 1) v = fmaxf(v, __shfl_down(v, off));
    if (lane == 0 && g == 0) sm[wid_l] = v;
    __syncthreads();
    const float pmax   = fmaxf(fmaxf(sm[0], sm[1]), fmaxf(sm[2], sm[3]));
    const float shift0 = 96.0f - pmax;

    {
        float pv = shift0 + pdb_a;
        p_s[g][tid_l]  = pv;
        pw_s[g][tid_l] = exp10f(pv / 10.0f);
        if (tid_l == 0) {
            float pv2 = shift0 + pdb_b;
            p_s[g][256]  = pv2;
            pw_s[g][256] = exp10f(pv2 / 10.0f);
        }
    }
    __syncthreads();

    // local-max + tonal masker level for bin = tid_l
    float m = -1e30f;
    int   pred = 0;
    if (tid_l >= 1 && tid_l <= 255) {
        float pc = p_s[g][tid_l];
        if (pc > p_s[g][tid_l - 1] && pc > p_s[g][tid_l + 1]) {
            m = 10.0f * log10f((pw_s[g][tid_l] + pw_s[g][tid_l - 1]) + pw_s[g][tid_l + 1]);
            if (m > tab[TAB_ATHDB + tid_l]) pred = 1;
        }
    }
    // ballot stream-compaction (stable in frequency order, per group)
    unsigned long long bal = __ballot(pred);
    if (lane == 0) wcnt[g][wid_l] = __popcll(bal);
    __syncthreads();
    int base = 0;
    for (int w = 0; w < wid_l; ++w) base += wcnt[g][w];
    const int n_total = wcnt[g][0] + wcnt[g][1] + wcnt[g][2] + wcnt[g][3];
    if (pred) {
        int pos = base + __popcll(bal & ((1ull << lane) - 1));
        bin_s[g][pos] = tid_l; mc_s[g][pos] = m; keep_s[g][pos] = 1;
    }
    __syncthreads();

    // pack (barkf[i], mc[i]) pairs + sentinel
    if (tid_l <= n_total && tid_l < 130) {
        pmk[g][tid_l] = (tid_l < n_total) ? make_float2(barkf[tid_l], mc_s[g][tid_l])
                                          : make_float2(1.0e30f, -1.0e30f);
    }
    __syncthreads();

    // the serial i_prev scans — one per group, running concurrently
    if (tid_l == 0 && n_total > 1) {
        int   i_prev = 0;
        float bp = pmk[g][0].x, mp = pmk[g][0].y;
        float2 c = pmk[g][1];
        for (int i = 1; i < n_total; ++i) {
            float2 nx = pmk[g][i + 1];
            bool close        = (c.x - bp) < 0.5f;
            bool prev_smaller = mp < c.y;
            if (close) {
                keep_s[g][prev_smaller ? i_prev : i] = 0;
                if (prev_smaller) {
                    ++i_prev;
                    if (i_prev == i) { bp = c.x; mp = c.y; }
                    else { float2 p = pmk[g][i_prev]; bp = p.x; mp = p.y; }
                }
            } else {
                i_prev = i; bp = c.x; mp = c.y;
            }
            c = nx;
        }
    }
    __syncthreads();

    // compact kept maskers, precompute per-masker terms
    int pred2 = (tid_l < n_total) && keep_s[g][tid_l];
    unsigned long long bal2 = __ballot(pred2);
    if (lane == 0) wcnt[g][wid_l] = __popcll(bal2);
    __syncthreads();
    int base2 = 0;
    for (int w = 0; w < wid_l; ++w) base2 += wcnt[g][w];
    const int nk = wcnt[g][0] + wcnt[g][1] + wcnt[g][2] + wcnt[g][3];
    if (pred2) {
        int pos = base2 + __popcll(bal2 & ((1ull << lane) - 1));
        int   fb = bin_s[g][tid_l];
        float mc = mc_s[g][tid_l];
        shift_s[g][pos] = mc + (-6.025f - 0.275f * barkf[fb]);
        barkm_s[g][pos] = barkf[fb];
        ups_s[g][pos]   = -27.0f + 0.37f * fmaxf(mc - 40.0f, 0.0f);
    }
    __syncthreads();

    // per-bin threshold power + loss (power domain, no log/exp round-trip)
    const float C = 3981071705.534973f / exp10f(pmax / 10.0f);  // 10^9.6/10^(pmax/10)
    float lsum = 0.0f;
    for (int f = tid_l; f < FBINS; f += 256) {
        float bf  = barkf[f];
        float acc = 0.0f;
        for (int k = 0; k < nk; ++k) {
            float dz    = bf - barkm_s[g][k];
            float slope = (dz > 0.0f) ? ups_s[g][k] : 27.0f;
            float tdb   = shift_s[g][k] + slope * dz;
            acc += exp10f(tdb / 10.0f);
        }
        float thrpow = acc + athp_s[f];
        float pds    = C * pd[frame * FBINS + f];
        lsum += fmaxf(pds - thrpow, 0.0f);
    }
    for (int off = 32; off > 0; off >>= 1) lsum += __shfl_down(lsum, off);
    if (lane == 0) red[g][wid_l] = lsum;
    __syncthreads();
    if (tid_l == 0)
        floss[frame] = (red[g][0] + red[g][1]) + (red[g][2] + red[g][3]);
}

// ---------------------------------------------------------------- kernel 4
__global__ __launch_bounds__(256) void k4_final(
    const float* __restrict__ floss, int nf, float* __restrict__ out)
{
    __shared__ float red[4];
    float s = 0.0f;
    for (int i = threadIdx.x; i < nf; i += 256) s += floss[i];
    for (int off = 32; off > 0; off >>= 1) s += __shfl_down(s, off);
    if ((threadIdx.x & 63) == 0) red[threadIdx.x >> 6] = s;
    __syncthreads();
    if (threadIdx.x == 0) {
        float total = (red[0] + red[1]) + (red[2] + red[3]);
        out[0] = 1e-6f * (total / (float)(nf * FBINS));
    }
}

// ---------------------------------------------------------------- launch
extern "C" void kernel_launch(void* const* d_in, const int* in_sizes, int n_in,
                              void* d_out, int out_size, void* d_ws, size_t ws_size,
                              hipStream_t stream)
{
    const float* x_adv = (const float*)d_in[0];
    const float* x_ref = (const float*)d_in[1];
    float*       out   = (float*)d_out;

    const int L  = in_sizes[0];
    const int nf = (L - 512) / 128 + 1;           // 1247 for L=160000

    // workspace layout (floats)
    float* ws      = (float*)d_ws;
    float* tab     = ws;                                   // TAB_FLOATS
    float* psd_db  = ws + TAB_FLOATS;                      // nf*257
    float* pd      = psd_db + (size_t)nf * FBINS;          // nf*257
    float* fmaxs   = pd + (size_t)nf * FBINS;              // nf
    float* floss   = fmaxs + nf;                           // nf

    const int k3_blocks = (nf + 1) / 2;           // 2 frames per block

    k0_init     <<<3,         256, 0, stream>>>(tab);
    k1_stft     <<<nf,        256, 0, stream>>>(x_adv, x_ref, tab, psd_db, pd, fmaxs);
    k3_threshold<<<k3_blocks, 512, 0, stream>>>(tab, psd_db, pd, fmaxs, nf, floss);
    k4_final    <<<1,         256, 0, stream>>>(floss, nf, out);
}